// Round 1
// 243.900 us; speedup vs baseline: 1.0019x; 1.0019x over previous
//
#include <hip/hip_runtime.h>

#define N_FLOWS 20
#define DIM 4
#define ITEMS 8
#define BLOCK 256

typedef float v2f __attribute__((ext_vector_type(2)));

// ---------------------------------------------------------------------------
// Setup: one tiny block precomputes all per-flow constants for the d-space
// recurrence. d_f := x - x0_f. Flow update:
//   s = 1 + beta/(alpha + ||d_f||),  d_{f+1} = s*d_f + c_f
// with c_f = x0_f - x0_{f+1} for f<19, and c_19 = x0_19 so that the final
// update directly produces x_20 (the output). This removes the per-flow
// x - x0 subtraction (2 packed subs) from the hot loop.
// ws layout per flow f (8 floats): [c.x, c.y, c.z, c.w, alpha, beta, 0, 0]
// slot f==N_FLOWS: [x0_0.x, x0_0.y, x0_0.z, x0_0.w, 0,0,0,0]  (for d_0 init)
// ---------------------------------------------------------------------------
__global__ void radial_setup(const float* __restrict__ x0s,
                             const float* __restrict__ alpha_primes,
                             const float* __restrict__ beta_primes,
                             float* __restrict__ ws) {
    int f = threadIdx.x;
    if (f < N_FLOWS) {
        float alpha = __logf(1.0f + __expf(alpha_primes[f]));
        float beta  = __logf(1.0f + __expf(beta_primes[f])) - alpha;
        float* p = ws + 8 * f;
        const bool last = (f == N_FLOWS - 1);
#pragma unroll
        for (int j = 0; j < 4; ++j)
            p[j] = x0s[4 * f + j] - (last ? 0.0f : x0s[4 * (f + 1) + j]);
        p[4] = alpha;
        p[5] = beta;
        p[6] = 0.0f;
        p[7] = 0.0f;
    } else if (f == N_FLOWS) {
        float* p = ws + 8 * N_FLOWS;
        p[0] = x0s[0]; p[1] = x0s[1]; p[2] = x0s[2]; p[3] = x0s[3];
        p[4] = 0.0f; p[5] = 0.0f; p[6] = 0.0f; p[7] = 0.0f;
    }
}

// ---------------------------------------------------------------------------
// Main: 20 chained radial flows in d-space. VALU-issue-bound.
// Per flow-item: pk_mul + pk_fma + add(r2) + v_sqrt + add(alpha+r) + v_rcp
//              + v_fma(s = beta*inv + 1) + 2x pk_fma (d = s*d + c)
// = 9 VALU instrs (11 full-rate scalar-equiv + 2 trans), down from 11 instrs
// (15 scalar-equiv + 2 trans) in the x-space form.
// No bounds check: grid covers exact tiles only; tail kernel handles the rest.
// ---------------------------------------------------------------------------
__global__ __launch_bounds__(BLOCK) void radial_main(
    const float4* __restrict__ Xv,
    const float4* __restrict__ P,   // ws as float4: P[2f]=c_f, P[2f+1]={alpha,beta,_,_}, P[40]=x0_0
    float4* __restrict__ Ov)
{
    const unsigned base = blockIdx.x * (BLOCK * ITEMS) + threadIdx.x;

    float4 z = P[2 * N_FLOWS];      // x0_0 (uniform -> s_load)
    v2f z01 = (v2f){z.x, z.y};
    v2f z23 = (v2f){z.z, z.w};

    v2f a[ITEMS], b[ITEMS];
#pragma unroll
    for (int i = 0; i < ITEMS; ++i) {
        float4 v = Xv[base + i * BLOCK];
        a[i] = (v2f){v.x, v.y} - z01;   // d_0 = x - x0_0 (once, amortized over 20 flows)
        b[i] = (v2f){v.z, v.w} - z23;
    }

#pragma unroll
    for (int f = 0; f < N_FLOWS; ++f) {
        float4 c  = P[2 * f];       // uniform -> s_load
        float4 ab = P[2 * f + 1];
        v2f c01 = (v2f){c.x, c.y};
        v2f c23 = (v2f){c.z, c.w};
        float alpha = ab.x, beta = ab.y;
#pragma unroll
        for (int i = 0; i < ITEMS; ++i) {
            v2f q = a[i] * a[i];          // v_pk_mul_f32
            q += b[i] * b[i];             // v_pk_fma_f32
            float r2 = q.x + q.y;         // v_add_f32
            float r  = __builtin_amdgcn_sqrtf(r2);                    // v_sqrt_f32
            float s  = __builtin_fmaf(beta,
                                      __builtin_amdgcn_rcpf(alpha + r), // v_add + v_rcp
                                      1.0f);                            // v_fma_f32
            v2f sv = (v2f){s, s};
            a[i] = sv * a[i] + c01;       // v_pk_fma_f32 (d = s*d + c)
            b[i] = sv * b[i] + c23;
        }
    }

    // after f=19 (c_19 = x0_19), d IS x_20 -> store directly
#pragma unroll
    for (int i = 0; i < ITEMS; ++i) {
        float4 v;
        v.x = a[i].x; v.y = a[i].y; v.z = b[i].x; v.w = b[i].y;
        Ov[base + i * BLOCK] = v;
    }
}

// Generic tail: one guarded sample per thread (grid is 0 for BATCH=2^23).
// Same d-space math as radial_main.
__global__ void radial_tail(const float4* __restrict__ Xv,
                            const float4* __restrict__ P,
                            float4* __restrict__ Ov,
                            int start, int batch)
{
    int idx = start + blockIdx.x * blockDim.x + threadIdx.x;
    if (idx >= batch) return;
    float4 z = P[2 * N_FLOWS];
    float4 v = Xv[idx];
    float dx = v.x - z.x, dy = v.y - z.y, dz = v.z - z.z, dw = v.w - z.w;
#pragma unroll
    for (int f = 0; f < N_FLOWS; ++f) {
        float4 c  = P[2 * f];
        float4 ab = P[2 * f + 1];
        float r2 = dx * dx + dy * dy + dz * dz + dw * dw;
        float r  = __builtin_amdgcn_sqrtf(r2);
        float s  = __builtin_fmaf(ab.y, __builtin_amdgcn_rcpf(ab.x + r), 1.0f);
        dx = s * dx + c.x; dy = s * dy + c.y;
        dz = s * dz + c.z; dw = s * dw + c.w;
    }
    float4 o; o.x = dx; o.y = dy; o.z = dz; o.w = dw;
    Ov[idx] = o;
}

extern "C" void kernel_launch(void* const* d_in, const int* in_sizes, int n_in,
                              void* d_out, int out_size, void* d_ws, size_t ws_size,
                              hipStream_t stream) {
    const float* X   = (const float*)d_in[0];
    const float* x0s = (const float*)d_in[1];
    const float* ap  = (const float*)d_in[2];
    const float* bp  = (const float*)d_in[3];
    float* out = (float*)d_out;
    float* ws  = (float*)d_ws;

    int batch = in_sizes[0] / DIM; // 8388608

    radial_setup<<<1, 64, 0, stream>>>(x0s, ap, bp, ws);

    const int tile = BLOCK * ITEMS;
    int full_blocks = batch / tile;
    if (full_blocks > 0)
        radial_main<<<full_blocks, BLOCK, 0, stream>>>(
            (const float4*)X, (const float4*)ws, (float4*)out);

    int done = full_blocks * tile;
    int rem = batch - done;
    if (rem > 0)
        radial_tail<<<(rem + 255) / 256, 256, 0, stream>>>(
            (const float4*)X, (const float4*)ws, (float4*)out, done, batch);
}